// Round 7
// baseline (47.364 us; speedup 1.0000x reference)
//
#include <hip/hip_runtime.h>

// TiedCirculantSpectralFilter: B=512, D=1024, P=64, K=16, L_S=16
// Gram G[m,n] = sum_d X[d,m] * (gamma_d * X[d,n]) / 64  via bf16 MFMA,
// then 16 steps: hp <- hp - (1/16) A hp ; hk <- hk + (1/16) C hp.
//
// 640 thr / 10 waves, two groups (parity-owned chunks). Deep prefetch:
// each staging thread holds TWO register sets (8 fv4); on its turn for
// chunk q it stages q and re-issues the freed set for chunk q+4 ->
// loads outstanding ~2 full iterations (Little's law fix for the 4.2 TB/s
// burst-duty-cycle plateau seen in r3-r6). Fully unrolled loop so the
// set choice ((q>>1)&1) is compile-time.

namespace {
typedef __attribute__((ext_vector_type(8))) short bf16x8;
typedef __attribute__((ext_vector_type(4))) float f32x4;
typedef __attribute__((ext_vector_type(4))) float fv4;
typedef __attribute__((ext_vector_type(2))) unsigned uv2;

constexpr int kB  = 512;
constexpr int kD  = 1024;
constexpr int kP  = 64;
constexpr int kKK = 16;
constexpr int kLS = 16;
constexpr int kThreads = 640;           // 10 waves
constexpr int kKc = 64;                 // d-rows per chunk
constexpr int kNC = kD / kKc;           // 16 chunks

constexpr int TB    = 4096;             // gamma f32[1024] at byte 0
constexpr int ASZ   = 80 * 128;         // A tile [80 m][64 k] bf16, swizzled
constexpr int BSZ   = 64 * 128;         // B tile [64 n][64 k] bf16, gamma-weighted
constexpr int BUFSZ = ASZ + BSZ;        // 18432
constexpr int LDS_BYTES = TB + 2 * BUFSZ;  // 40960

__device__ __forceinline__ unsigned short bf16_bits(float x) {
  unsigned u = __builtin_bit_cast(unsigned, x);
  u += 0x7fffu + ((u >> 16) & 1u);   // round-to-nearest-even
  return (unsigned short)(u >> 16);
}
__device__ __forceinline__ unsigned bpack(float lo, float hi) {
  return (unsigned)bf16_bits(lo) | ((unsigned)bf16_bits(hi) << 16);
}
// bijective 16B-slot swizzle (bits [6:4] of the in-row byte col)
__device__ __forceinline__ int fswz(int r) {
  return ((r & 7) ^ ((r >> 2) & 7)) << 4;
}

__device__ __forceinline__ void stage_chunk(char* __restrict__ Ab, char* __restrict__ Bb,
                                            int ct, int kt,
                                            const fv4& v0, const fv4& v1,
                                            const fv4& v2, const fv4& v3,
                                            const fv4& g4) {
#pragma unroll
  for (int j = 0; j < 4; ++j) {
    const int m = 4 * ct + j;
    const int off = m * 128 + ((8 * kt) ^ fswz(m));
    uv2 wa; wa.x = bpack(v0[j], v1[j]); wa.y = bpack(v2[j], v3[j]);
    *reinterpret_cast<uv2*>(Ab + off) = wa;
    if (ct < 16) {
      uv2 wb; wb.x = bpack(g4[0] * v0[j], g4[1] * v1[j]);
      wb.y = bpack(g4[2] * v2[j], g4[3] * v3[j]);
      *reinterpret_cast<uv2*>(Bb + off) = wb;
    }
  }
}

#define ISSUE(q, S0, S1, S2, S3)                                   \
  { const int base_ = ((q) * kKc + 4 * kt) * 20 + ct;              \
    S0 = Xg[base_]; S1 = Xg[base_ + 20];                           \
    S2 = Xg[base_ + 40]; S3 = Xg[base_ + 60]; }

#define STAGE(q, S0, S1, S2, S3)                                   \
  { const fv4 g4_ = *reinterpret_cast<const fv4*>(gs + (q) * kKc + 4 * kt); \
    char* Ab_ = smem + TB + ((q) & 1) * BUFSZ;                     \
    stage_chunk(Ab_, Ab_ + ASZ, ct, kt, S0, S1, S2, S3, g4_); }

__global__ void __launch_bounds__(kThreads, 5)
tcsf_kernel(const float* __restrict__ X, const float* __restrict__ y,
            const float* __restrict__ gamma, float* __restrict__ out) {
  __shared__ __align__(16) char smem[LDS_BYTES];
  float* gs = reinterpret_cast<float*>(smem);

  const int t = threadIdx.x;
  const int b = blockIdx.x;
  const int l = t & 63;
  const int w = t >> 6;                 // 0..9
  const int grp = (w >= 5) ? 1 : 0;     // owns chunks with parity == grp
  const int slab = grp ? (w - 5) : w;   // m-rows 16*slab..+15
  const int tg = grp ? (t - 320) : t;
  const int ct = tg % 20;               // m-quad
  const int kt = tg / 20;               // k-quad (0..15)

  float yv = 0.f;
  if (t < kP) yv = y[b * kP + t];
  for (int i = t; i < kD; i += kThreads) gs[i] = gamma[i];

  const fv4* Xg = reinterpret_cast<const fv4*>(X) + (size_t)b * (kD * 80 / 4);

  f32x4 acc[4];
#pragma unroll
  for (int nt = 0; nt < 4; ++nt) acc[nt] = (f32x4)(0.f);

  // two register load-sets per staging thread
  fv4 a0, a1, a2, a3;   // set A: chunks with (q>>1)&1 == 0
  fv4 b0, b1, b2, b3;   // set B: chunks with (q>>1)&1 == 1

  // prologue: g0 issues ch0(A), ch2(B); g1 issues ch1(A), ch3(B)
  ISSUE(grp, a0, a1, a2, a3);
  ISSUE(grp + 2, b0, b1, b2, b3);
  __syncthreads();  // gamma visible
  if (!grp) {       // stage chunk 0 from set A, re-issue A for chunk 4
    STAGE(0, a0, a1, a2, a3);
    ISSUE(4, a0, a1, a2, a3);
  }
  __syncthreads();  // buf0 staged

  // fragment read offsets (constant per thread)
  const int rA = 16 * slab + (l & 15);
  const int cbb = grp * 64 + (l >> 4) * 16;   // k-half + k-quad byte offset
  const int offA = rA * 128 + (cbb ^ fswz(rA));
  int offB[4];
#pragma unroll
  for (int nt = 0; nt < 4; ++nt) {
    const int rB = 16 * nt + (l & 15);
    offB[nt] = rB * 128 + (cbb ^ fswz(rB));
  }

  // main loop, fully unrolled: on own turn stage q=c+1 from set (q>>1)&1,
  // then re-issue that set for chunk q+4. One barrier per chunk.
#pragma unroll
  for (int c = 0; c < kNC; ++c) {
    const int q = c + 1;
    if (q < kNC && grp == (q & 1)) {
      if (((q >> 1) & 1) == 0) {
        STAGE(q, a0, a1, a2, a3);
        if (q + 4 < kNC) ISSUE(q + 4, a0, a1, a2, a3);
      } else {
        STAGE(q, b0, b1, b2, b3);
        if (q + 4 < kNC) ISSUE(q + 4, b0, b1, b2, b3);
      }
    }
    const char* Ab = smem + TB + (c & 1) * BUFSZ;
    const char* Bb = Ab + ASZ;
    const bf16x8 a = *reinterpret_cast<const bf16x8*>(Ab + offA);
#pragma unroll
    for (int nt = 0; nt < 4; ++nt) {
      const bf16x8 bb = *reinterpret_cast<const bf16x8*>(Bb + offB[nt]);
      acc[nt] = __builtin_amdgcn_mfma_f32_16x16x32_bf16(a, bb, acc[nt], 0, 0, 0);
    }
    __syncthreads();
  }

  // ---- merge k-halves + G -> LDS ----
  // C/D layout: col = lane&15, row = (lane>>4)*4 + reg
  float* Gl = reinterpret_cast<float*>(smem + TB);  // [80][65] padded
  float* hp = Gl + 80 * 65;                         // hp[2][64]
  constexpr float invP = 1.0f / 64.0f;
  if (grp) {
#pragma unroll
    for (int nt = 0; nt < 4; ++nt)
#pragma unroll
      for (int r = 0; r < 4; ++r)
        Gl[(16 * slab + (l >> 4) * 4 + r) * 65 + 16 * nt + (l & 15)] = acc[nt][r];
  }
  __syncthreads();
  if (!grp) {
#pragma unroll
    for (int nt = 0; nt < 4; ++nt)
#pragma unroll
      for (int r = 0; r < 4; ++r) {
        const int idx = (16 * slab + (l >> 4) * 4 + r) * 65 + 16 * nt + (l & 15);
        Gl[idx] = (Gl[idx] + acc[nt][r]) * invP;
      }
  }
  if (t < kP) hp[t] = yv;  // hp[0]
  __syncthreads();

  // ---- phase 2: 16 steps, 8 threads per row, hp double-buffered ----
  const int m = t >> 3;        // 0..79
  const int part = t & 7;
  const float* Grow = Gl + m * 65 + part * 8;
  float hk = 0.f;
  constexpr float invL = 1.0f / kLS;
  for (int s = 0; s < kLS; ++s) {
    const float* hpc = hp + (s & 1) * kP;
    const float* hpp = hpc + part * 8;
    float d0 = 0.f, d1 = 0.f, d2 = 0.f, d3 = 0.f;
#pragma unroll
    for (int i = 0; i < 8; i += 4) {
      d0 = fmaf(Grow[i + 0], hpp[i + 0], d0);
      d1 = fmaf(Grow[i + 1], hpp[i + 1], d1);
      d2 = fmaf(Grow[i + 2], hpp[i + 2], d2);
      d3 = fmaf(Grow[i + 3], hpp[i + 3], d3);
    }
    float dot = (d0 + d1) + (d2 + d3);
    dot += __shfl_xor(dot, 1);
    dot += __shfl_xor(dot, 2);
    dot += __shfl_xor(dot, 4);
    if (part == 0) {
      if (m < kP) hp[((s + 1) & 1) * kP + m] = hpc[m] - invL * dot;
      else        hk += invL * dot;
    }
    __syncthreads();
  }
  if (part == 0 && m >= kP) out[b * kKK + (m - kP)] = hk;
}

}  // namespace

extern "C" void kernel_launch(void* const* d_in, const int* in_sizes, int n_in,
                              void* d_out, int out_size, void* d_ws, size_t ws_size,
                              hipStream_t stream) {
  const float* X     = (const float*)d_in[0];  // [512,1024,80]
  const float* y     = (const float*)d_in[1];  // [512,64]
  const float* gamma = (const float*)d_in[2];  // [1024]
  float* out = (float*)d_out;                  // [512,16]
  tcsf_kernel<<<dim3(kB), dim3(kThreads), 0, stream>>>(X, y, gamma, out);
}

// Round 9
// 36.476 us; speedup vs baseline: 1.2985x; 1.2985x over previous
//
#include <hip/hip_runtime.h>
#include <hip/hip_bf16.h>

// TiedCirculantSpectralFilter: B=512, D=1024, P=64, K=16, L_S=16
// Gram G[m,n] = sum_d X[d,m] * (gamma_d * X[d,n]) / 64  via bf16 MFMA,
// then 16 steps: hp <- hp - (1/16) A hp ; hk <- hk + (1/16) C hp.
//
// r3 structure (320 thr / 5 waves, lockstep, 2 barriers/chunk) plus:
//  - bf16 pack via scalar __float2bfloat16 casts (compiler fuses pairs into
//    v_cvt_pk_bf16_f32 per m240; 3-op bit-trick per value was 3x VALU)
//  - phase 2: G row hoisted to registers before the step loop (step-invariant;
//    compiler couldn't prove no-alias vs hp writes -> was re-reading 16
//    ds_read_b32 x 16 steps). G stride 68 keeps 16B alignment so G and hp
//    move as b128; 17-bank row stride stays conflict-free.

namespace {
typedef __attribute__((ext_vector_type(8))) short bf16x8;
typedef __attribute__((ext_vector_type(4))) float f32x4;
typedef __attribute__((ext_vector_type(4))) float fv4;
typedef __attribute__((ext_vector_type(2))) unsigned uv2;

constexpr int kB  = 512;
constexpr int kD  = 1024;
constexpr int kP  = 64;
constexpr int kKK = 16;
constexpr int kLS = 16;
constexpr int kThreads = 320;           // 5 waves
constexpr int kKc = 64;                 // d-rows per chunk
constexpr int kNC = kD / kKc;           // 16 chunks

constexpr int TB    = 4096;             // gamma f32[1024] at byte 0
constexpr int ASZ   = 80 * 128;         // A tile [80 m][64 k] bf16, swizzled
constexpr int BSZ   = 64 * 128;         // B tile [64 n][64 k] bf16, gamma-weighted
constexpr int BUFSZ = ASZ + BSZ;        // 18432
constexpr int LDS_BYTES = TB + 2 * BUFSZ;  // 40960
constexpr int GSTRIDE = 68;             // floats; 16B-aligned rows, odd bank stride

__device__ __forceinline__ unsigned bpack(float lo, float hi) {
  __hip_bfloat16 hl = __float2bfloat16(lo);
  __hip_bfloat16 hh = __float2bfloat16(hi);
  unsigned short ul, uh;
  __builtin_memcpy(&ul, &hl, 2);
  __builtin_memcpy(&uh, &hh, 2);
  return (unsigned)ul | ((unsigned)uh << 16);
}

__global__ void __launch_bounds__(kThreads)
tcsf_kernel(const float* __restrict__ X, const float* __restrict__ y,
            const float* __restrict__ gamma, float* __restrict__ out) {
  __shared__ __align__(16) char smem[LDS_BYTES];
  float* gs = reinterpret_cast<float*>(smem);

  const int t = threadIdx.x;
  const int b = blockIdx.x;
  const int l = t & 63;
  const int w = t >> 6;            // wave 0..4 -> m-rows 16w..16w+15

  float yv = 0.f;
  if (t < kP) yv = y[b * kP + t];
  for (int i = t; i < kD; i += kThreads) gs[i] = gamma[i];

  const fv4* Xg = reinterpret_cast<const fv4*>(X) + (size_t)b * (kD * 80 / 4);

  // staging decomposition: thread t handles k = 4*kt + i (i=0..3), m = 4*ct + j
  const int ct = t % 20;           // m-quad
  const int kt = t / 20;           // k-quad (0..15)

  f32x4 acc[4];
#pragma unroll
  for (int nt = 0; nt < 4; ++nt) acc[nt] = (f32x4)(0.f);

  fv4 v0, v1, v2, v3;
  fv4 g4;

  __syncthreads();  // gamma visible

  // ---- prologue: load + stage chunk 0 into buf 0 ----
  {
    v0 = Xg[(4 * kt) * 20 + ct];
    v1 = Xg[(4 * kt) * 20 + ct + 20];
    v2 = Xg[(4 * kt) * 20 + ct + 40];
    v3 = Xg[(4 * kt) * 20 + ct + 60];
    g4 = *reinterpret_cast<const fv4*>(gs + 4 * kt);
    char* Ab = smem + TB;
    char* Bb = Ab + ASZ;
#pragma unroll
    for (int j = 0; j < 4; ++j) {
      const int m = 4 * ct + j;
      const int off = m * 128 + ((8 * kt) ^ ((m & 7) << 4));
      uv2 wa; wa.x = bpack(v0[j], v1[j]); wa.y = bpack(v2[j], v3[j]);
      *reinterpret_cast<uv2*>(Ab + off) = wa;
      if (ct < 16) {
        uv2 wb; wb.x = bpack(g4[0] * v0[j], g4[1] * v1[j]);
        wb.y = bpack(g4[2] * v2[j], g4[3] * v3[j]);
        *reinterpret_cast<uv2*>(Bb + off) = wb;
      }
    }
  }

  // fragment read addressing (constant per thread)
  const int rA = 16 * w + (l & 15);
  const int colb = (l >> 4) * 16;
  const int fswz = (l & 7) << 4;   // rA&7 == l&7, rB&7 == l&7

  // ---- main loop over 16 chunks, double-buffered, 2 barriers/chunk ----
  for (int c = 0; c < kNC; ++c) {
    if (c + 1 < kNC) {  // issue next-chunk loads; latency hides under compute
      const int base = ((c + 1) * kKc + 4 * kt) * 20 + ct;
      v0 = Xg[base]; v1 = Xg[base + 20]; v2 = Xg[base + 40]; v3 = Xg[base + 60];
      g4 = *reinterpret_cast<const fv4*>(gs + (c + 1) * kKc + 4 * kt);
    }
    __syncthreads();  // buf[c&1] staging complete
    {
      const char* Ab = smem + TB + (c & 1) * BUFSZ;
      const char* Bb = Ab + ASZ;
#pragma unroll
      for (int ks = 0; ks < 2; ++ks) {
        const int cb = ks * 64 + colb;
        const bf16x8 a = *reinterpret_cast<const bf16x8*>(Ab + rA * 128 + (cb ^ fswz));
#pragma unroll
        for (int nt = 0; nt < 4; ++nt) {
          const bf16x8 bb = *reinterpret_cast<const bf16x8*>(
              Bb + (16 * nt + (l & 15)) * 128 + (cb ^ fswz));
          acc[nt] = __builtin_amdgcn_mfma_f32_16x16x32_bf16(a, bb, acc[nt], 0, 0, 0);
        }
      }
    }
    __syncthreads();  // all waves done reading buf[(c+1)&1]
    if (c + 1 < kNC) {
      char* Ab = smem + TB + ((c + 1) & 1) * BUFSZ;
      char* Bb = Ab + ASZ;
#pragma unroll
      for (int j = 0; j < 4; ++j) {
        const int m = 4 * ct + j;
        const int off = m * 128 + ((8 * kt) ^ ((m & 7) << 4));
        uv2 wa; wa.x = bpack(v0[j], v1[j]); wa.y = bpack(v2[j], v3[j]);
        *reinterpret_cast<uv2*>(Ab + off) = wa;
        if (ct < 16) {
          uv2 wb; wb.x = bpack(g4[0] * v0[j], g4[1] * v1[j]);
          wb.y = bpack(g4[2] * v2[j], g4[3] * v3[j]);
          *reinterpret_cast<uv2*>(Bb + off) = wb;
        }
      }
    }
  }

  // ---- G -> LDS ----
  // C/D layout: col = lane&15, row = (lane>>4)*4 + reg
  float* Gl = reinterpret_cast<float*>(smem + TB);  // [80][GSTRIDE]
  float* hp = Gl + 80 * GSTRIDE;                    // [64]
  constexpr float invP = 1.0f / 64.0f;
#pragma unroll
  for (int nt = 0; nt < 4; ++nt)
#pragma unroll
    for (int r = 0; r < 4; ++r)
      Gl[(16 * w + (l >> 4) * 4 + r) * GSTRIDE + 16 * nt + (l & 15)] =
          acc[nt][r] * invP;

  if (t < kP) hp[t] = yv;
  __syncthreads();

  // ---- phase 2: 16 steps, 4 threads per row; G row in registers ----
  const int m = t >> 2;        // 0..79
  const int part = t & 3;
  const fv4* Grow4 = reinterpret_cast<const fv4*>(Gl + m * GSTRIDE + part * 16);
  const fv4* hpp4  = reinterpret_cast<const fv4*>(hp + part * 16);
  const fv4 G0 = Grow4[0], G1 = Grow4[1], G2 = Grow4[2], G3 = Grow4[3];
  float hk = 0.f;
  constexpr float invL = 1.0f / kLS;
  for (int s = 0; s < kLS; ++s) {
    const fv4 h0 = hpp4[0], h1 = hpp4[1], h2 = hpp4[2], h3 = hpp4[3];
    float d0 = 0.f, d1 = 0.f, d2 = 0.f, d3 = 0.f;
#pragma unroll
    for (int i = 0; i < 4; ++i) {
      d0 = fmaf(G0[i], h0[i], d0);
      d1 = fmaf(G1[i], h1[i], d1);
      d2 = fmaf(G2[i], h2[i], d2);
      d3 = fmaf(G3[i], h3[i], d3);
    }
    float dot = (d0 + d1) + (d2 + d3);
    dot += __shfl_xor(dot, 1);
    dot += __shfl_xor(dot, 2);
    __syncthreads();  // all reads of hp for this step complete
    if (part == 0) {
      if (m < kP) hp[m] -= invL * dot;   // unique writer per m
      else        hk   += invL * dot;
    }
    __syncthreads();  // hp update visible for next step
  }
  if (part == 0 && m >= kP) out[b * kKK + (m - kP)] = hk;
}

}  // namespace

extern "C" void kernel_launch(void* const* d_in, const int* in_sizes, int n_in,
                              void* d_out, int out_size, void* d_ws, size_t ws_size,
                              hipStream_t stream) {
  const float* X     = (const float*)d_in[0];  // [512,1024,80]
  const float* y     = (const float*)d_in[1];  // [512,64]
  const float* gamma = (const float*)d_in[2];  // [1024]
  float* out = (float*)d_out;                  // [512,16]
  tcsf_kernel<<<dim3(kB), dim3(kThreads), 0, stream>>>(X, y, gamma, out);
}